// Round 1
// baseline (1617.268 us; speedup 1.0000x reference)
//
#include <hip/hip_runtime.h>
#include <math.h>

#define B 8
#define S 2048
#define KIN 512
#define NIN 2048
#define NP 4096
#define HID 4096
#define DM 1024
#define TOPK 256

__device__ __forceinline__ float gelu_exact(float x) {
    // matches jax.nn.gelu(approximate=False): x * Phi(x)
    return 0.5f * x * (1.0f + erff(x * 0.70710678118654752440f));
}

__device__ __forceinline__ void atomicMaxFloat(float* addr, float val) {
    // int-trick float max; init value must be -inf bits (0xFF800000)
    if (val >= 0.0f) atomicMax((int*)addr, __float_as_int(val));
    else             atomicMin((unsigned int*)addr, __float_as_uint(val));
}

__global__ __launch_bounds__(256) void init_kernel(float* scores, float* mask, int* selcnt) {
    int t = blockIdx.x * blockDim.x + threadIdx.x;
    if (t < B * NP)  scores[t] = __int_as_float(0xFF800000);  // -inf
    if (t < B * NIN) mask[t] = 0.0f;
    if (t < B)       selcnt[t] = 0;
}

__global__ __launch_bounds__(256) void scatter_mask(const int* __restrict__ idx, float* __restrict__ mask) {
    int t = blockIdx.x * blockDim.x + threadIdx.x;
    if (t >= B * KIN) return;
    int b = t / KIN;
    mask[b * NIN + idx[t]] = 1.0f;  // set semantics; duplicates harmless
}

// Wg[b][p][j] = cw[p][idx[b][j]]  — coalesced writes, row-local gathered reads
__global__ __launch_bounds__(256) void gather_w(const float* __restrict__ cw,
                                                const int* __restrict__ idx,
                                                float* __restrict__ wg) {
    __shared__ int sidx[KIN];
    int b = blockIdx.y;
    int p0 = blockIdx.x * 8;
    for (int j = threadIdx.x; j < KIN; j += 256) sidx[j] = idx[b * KIN + j];
    __syncthreads();
    for (int r = 0; r < 8; ++r) {
        int p = p0 + r;
        const float* row = cw + (size_t)p * NIN;
        float* orow = wg + ((size_t)b * NP + p) * KIN;
        for (int j = threadIdx.x; j < KIN; j += 256) orow[j] = row[sidx[j]];
    }
}

// z tile 64x64, gelu, per-p max over s, atomic-max into scores. fp32 exact path.
__global__ __launch_bounds__(256) void gemm_scores(const float* __restrict__ A,
                                                   const float* __restrict__ Wg,
                                                   float* __restrict__ scores) {
    __shared__ float As[16][64];
    __shared__ float Ws[16][64];
    __shared__ float red[16][64];
    int b = blockIdx.z;
    int s0 = blockIdx.x * 64;
    int p0 = blockIdx.y * 64;
    int tid = threadIdx.x;
    int tx = tid & 15, ty = tid >> 4;
    int lrow = tid >> 2, lq = tid & 3;
    const float* Abase = A + ((size_t)b * S + s0) * KIN;
    const float* Wbase = Wg + ((size_t)b * NP + p0) * KIN;
    float acc[4][4] = {};
    for (int k0 = 0; k0 < KIN; k0 += 16) {
        float4 av = *(const float4*)(Abase + (size_t)lrow * KIN + k0 + lq * 4);
        float4 wv = *(const float4*)(Wbase + (size_t)lrow * KIN + k0 + lq * 4);
        __syncthreads();
        As[lq * 4 + 0][lrow] = av.x; As[lq * 4 + 1][lrow] = av.y;
        As[lq * 4 + 2][lrow] = av.z; As[lq * 4 + 3][lrow] = av.w;
        Ws[lq * 4 + 0][lrow] = wv.x; Ws[lq * 4 + 1][lrow] = wv.y;
        Ws[lq * 4 + 2][lrow] = wv.z; Ws[lq * 4 + 3][lrow] = wv.w;
        __syncthreads();
#pragma unroll
        for (int kk = 0; kk < 16; ++kk) {
            float4 a = *(const float4*)&As[kk][ty * 4];
            float4 w = *(const float4*)&Ws[kk][tx * 4];
            float ar[4] = {a.x, a.y, a.z, a.w};
            float wr[4] = {w.x, w.y, w.z, w.w};
#pragma unroll
            for (int i = 0; i < 4; ++i)
#pragma unroll
                for (int j = 0; j < 4; ++j) acc[i][j] += ar[i] * wr[j];
        }
    }
    __syncthreads();
    float m[4];
#pragma unroll
    for (int j = 0; j < 4; ++j) {
        float mm = -INFINITY;
#pragma unroll
        for (int i = 0; i < 4; ++i) mm = fmaxf(mm, gelu_exact(acc[i][j]));
        m[j] = mm;
    }
#pragma unroll
    for (int j = 0; j < 4; ++j) red[ty][tx * 4 + j] = m[j];
    __syncthreads();
    if (tid < 64) {
        float mm = -INFINITY;
#pragma unroll
        for (int r = 0; r < 16; ++r) mm = fmaxf(mm, red[r][tid]);
        atomicMaxFloat(&scores[(size_t)b * NP + p0 + tid], mm);
    }
}

// h[b][i] = gelu(sum_c mask[b][c]*w1[i][c] + b1[i])
__global__ __launch_bounds__(256) void mlp1(const float* __restrict__ mask,
                                            const float* __restrict__ w1,
                                            const float* __restrict__ b1,
                                            float* __restrict__ h) {
    __shared__ float sm[NIN];
    int b = blockIdx.y;
    int i = blockIdx.x * 256 + threadIdx.x;
    for (int c = threadIdx.x; c < NIN; c += 256) sm[c] = mask[b * NIN + c];
    __syncthreads();
    const float* row = w1 + (size_t)i * NIN;
    float acc = 0.f;
    for (int c = 0; c < NIN; c += 4) {
        float4 w = *(const float4*)(row + c);
        acc += sm[c] * w.x + sm[c + 1] * w.y + sm[c + 2] * w.z + sm[c + 3] * w.w;
    }
    h[b * HID + i] = gelu_exact(acc + b1[i]);
}

// rel = h@w2.T + b2 ; scores *= sigmoid(rel)  (in place -> final_scores)
__global__ __launch_bounds__(256) void mlp2(const float* __restrict__ h,
                                            const float* __restrict__ w2,
                                            const float* __restrict__ b2,
                                            float* __restrict__ scores) {
    __shared__ float sh[HID];
    int b = blockIdx.y;
    int p = blockIdx.x * 256 + threadIdx.x;
    for (int c = threadIdx.x; c < HID; c += 256) sh[c] = h[b * HID + c];
    __syncthreads();
    const float* row = w2 + (size_t)p * HID;
    float acc = 0.f;
    for (int c = 0; c < HID; c += 4) {
        float4 w = *(const float4*)(row + c);
        acc += sh[c] * w.x + sh[c + 1] * w.y + sh[c + 2] * w.z + sh[c + 3] * w.w;
    }
    float rel = acc + b2[p];
    float sg = 1.0f / (1.0f + expf(-rel));
    scores[(size_t)b * NP + p] *= sg;
}

// Exact top-k set via rank counting with jax.lax.top_k tie-break (lower index wins).
__global__ __launch_bounds__(256) void topk_select(const float* __restrict__ scores,
                                                   int* __restrict__ selidx,
                                                   int* __restrict__ selcnt) {
    __shared__ float sc[NP];
    int b = blockIdx.y;
    int p = blockIdx.x * 256 + threadIdx.x;
    for (int c = threadIdx.x; c < NP; c += 256) sc[c] = scores[(size_t)b * NP + c];
    __syncthreads();
    float my = sc[p];
    int cnt = 0;
    for (int q = 0; q < NP; ++q) {
        float v = sc[q];
        cnt += (v > my) || (v == my && q < p);
    }
    if (cnt < TOPK) {
        int pos = atomicAdd(&selcnt[b], 1);
        selidx[b * TOPK + pos] = p;  // order arbitrary; final einsum is a sum
    }
}

// selpa[b][s][kk] = gelu(sum_j A[b][s][j] * Wg[b][sel[kk]][j])
__global__ __launch_bounds__(256) void selpa_gemm(const float* __restrict__ A,
                                                  const float* __restrict__ Wg,
                                                  const int* __restrict__ selidx,
                                                  float* __restrict__ selpa) {
    __shared__ float As[16][64];
    __shared__ float Ws[16][64];
    __shared__ int sel[64];
    int b = blockIdx.z;
    int s0 = blockIdx.x * 64;
    int c0 = blockIdx.y * 64;  // selected-column tile
    int tid = threadIdx.x;
    if (tid < 64) sel[tid] = selidx[b * TOPK + c0 + tid];
    __syncthreads();
    int tx = tid & 15, ty = tid >> 4;
    int lrow = tid >> 2, lq = tid & 3;
    const float* Abase = A + ((size_t)b * S + s0) * KIN;
    const float* Wbase = Wg + (size_t)b * NP * KIN;
    int selrow = sel[lrow];
    float acc[4][4] = {};
    for (int k0 = 0; k0 < KIN; k0 += 16) {
        float4 av = *(const float4*)(Abase + (size_t)lrow * KIN + k0 + lq * 4);
        float4 wv = *(const float4*)(Wbase + (size_t)selrow * KIN + k0 + lq * 4);
        __syncthreads();
        As[lq * 4 + 0][lrow] = av.x; As[lq * 4 + 1][lrow] = av.y;
        As[lq * 4 + 2][lrow] = av.z; As[lq * 4 + 3][lrow] = av.w;
        Ws[lq * 4 + 0][lrow] = wv.x; Ws[lq * 4 + 1][lrow] = wv.y;
        Ws[lq * 4 + 2][lrow] = wv.z; Ws[lq * 4 + 3][lrow] = wv.w;
        __syncthreads();
#pragma unroll
        for (int kk = 0; kk < 16; ++kk) {
            float4 a = *(const float4*)&As[kk][ty * 4];
            float4 w = *(const float4*)&Ws[kk][tx * 4];
            float ar[4] = {a.x, a.y, a.z, a.w};
            float wr[4] = {w.x, w.y, w.z, w.w};
#pragma unroll
            for (int i = 0; i < 4; ++i)
#pragma unroll
                for (int j = 0; j < 4; ++j) acc[i][j] += ar[i] * wr[j];
        }
    }
#pragma unroll
    for (int i = 0; i < 4; ++i)
#pragma unroll
        for (int j = 0; j < 4; ++j)
            selpa[((size_t)b * S + s0 + ty * 4 + i) * TOPK + c0 + tx * 4 + j] =
                gelu_exact(acc[i][j]);
}

// out[b][s][d] = sum_kk selpa[b][s][kk] * proj[sel[kk]][d]
__global__ __launch_bounds__(256) void out_gemm(const float* __restrict__ selpa,
                                                const float* __restrict__ proj,
                                                const int* __restrict__ selidx,
                                                float* __restrict__ out) {
    __shared__ float As[16][64];
    __shared__ float Bs[16][64];
    __shared__ int sel[TOPK];
    int b = blockIdx.z;
    int s0 = blockIdx.x * 64;
    int d0 = blockIdx.y * 64;
    int tid = threadIdx.x;
    sel[tid] = selidx[b * TOPK + tid];
    __syncthreads();
    int tx = tid & 15, ty = tid >> 4;
    int lrow = tid >> 2, lq = tid & 3;   // A-tile load mapping
    int krow = tid >> 4, dq = tid & 15;  // B-tile load mapping
    const float* Abase = selpa + ((size_t)b * S + s0) * TOPK;
    float acc[4][4] = {};
    for (int k0 = 0; k0 < TOPK; k0 += 16) {
        float4 av = *(const float4*)(Abase + (size_t)lrow * TOPK + k0 + lq * 4);
        int pk = sel[k0 + krow];
        float4 bv = *(const float4*)(proj + (size_t)pk * DM + d0 + dq * 4);
        __syncthreads();
        As[lq * 4 + 0][lrow] = av.x; As[lq * 4 + 1][lrow] = av.y;
        As[lq * 4 + 2][lrow] = av.z; As[lq * 4 + 3][lrow] = av.w;
        *(float4*)&Bs[krow][dq * 4] = bv;
        __syncthreads();
#pragma unroll
        for (int kk = 0; kk < 16; ++kk) {
            float4 a = *(const float4*)&As[kk][ty * 4];
            float4 w = *(const float4*)&Bs[kk][tx * 4];
            float ar[4] = {a.x, a.y, a.z, a.w};
            float wr[4] = {w.x, w.y, w.z, w.w};
#pragma unroll
            for (int i = 0; i < 4; ++i)
#pragma unroll
                for (int j = 0; j < 4; ++j) acc[i][j] += ar[i] * wr[j];
        }
    }
#pragma unroll
    for (int i = 0; i < 4; ++i)
#pragma unroll
        for (int j = 0; j < 4; ++j)
            out[((size_t)b * S + s0 + ty * 4 + i) * DM + d0 + tx * 4 + j] = acc[i][j];
}

extern "C" void kernel_launch(void* const* d_in, const int* in_sizes, int n_in,
                              void* d_out, int out_size, void* d_ws, size_t ws_size,
                              hipStream_t stream) {
    const float* A    = (const float*)d_in[0];
    const int*   idx  = (const int*)d_in[1];
    // d_in[2] = k (always 256 for this problem)
    const float* cw   = (const float*)d_in[3];
    const float* proj = (const float*)d_in[4];
    const float* w1   = (const float*)d_in[5];
    const float* b1   = (const float*)d_in[6];
    const float* w2   = (const float*)d_in[7];
    const float* b2   = (const float*)d_in[8];
    float* out = (float*)d_out;

    char* ws = (char*)d_ws;
    size_t off = 0;
    auto alloc = [&](size_t bytes) {
        void* p = ws + off;
        off += (bytes + 255) & ~(size_t)255;
        return p;
    };
    float* wg     = (float*)alloc((size_t)B * NP * KIN * 4);   // 67 MB
    float* selpa  = (float*)alloc((size_t)B * S * TOPK * 4);   // 16.8 MB
    float* scores = (float*)alloc((size_t)B * NP * 4);
    float* mask   = (float*)alloc((size_t)B * NIN * 4);
    float* h      = (float*)alloc((size_t)B * HID * 4);
    int*   selidx = (int*)alloc((size_t)B * TOPK * 4);
    int*   selcnt = (int*)alloc((size_t)B * 4);

    init_kernel<<<dim3((B * NP + 255) / 256), 256, 0, stream>>>(scores, mask, selcnt);
    scatter_mask<<<dim3((B * KIN + 255) / 256), 256, 0, stream>>>(idx, mask);
    gather_w<<<dim3(NP / 8, B), 256, 0, stream>>>(cw, idx, wg);
    gemm_scores<<<dim3(S / 64, NP / 64, B), 256, 0, stream>>>(A, wg, scores);
    mlp1<<<dim3(HID / 256, B), 256, 0, stream>>>(mask, w1, b1, h);
    mlp2<<<dim3(NP / 256, B), 256, 0, stream>>>(h, w2, b2, scores);
    topk_select<<<dim3(NP / 256, B), 256, 0, stream>>>(scores, selidx, selcnt);
    selpa_gemm<<<dim3(S / 64, TOPK / 64, B), 256, 0, stream>>>(A, wg, selidx, selpa);
    out_gemm<<<dim3(S / 64, DM / 64, B), 256, 0, stream>>>(selpa, proj, selidx, out);
}

// Round 2
// 829.632 us; speedup vs baseline: 1.9494x; 1.9494x over previous
//
#include <hip/hip_runtime.h>
#include <math.h>

#define B 8
#define S 2048
#define KIN 512
#define NIN 2048
#define NP 4096
#define HID 4096
#define DM 1024
#define TOPK 256

typedef __bf16 bf16x8 __attribute__((ext_vector_type(8)));
typedef __bf16 bf16x4 __attribute__((ext_vector_type(4)));
typedef float f32x4 __attribute__((ext_vector_type(4)));

__device__ __forceinline__ float gelu_exact(float x) {
    return 0.5f * x * (1.0f + erff(x * 0.70710678118654752440f));
}

__device__ __forceinline__ void atomicMaxFloat(float* addr, float val) {
    if (val >= 0.0f) atomicMax((int*)addr, __float_as_int(val));
    else             atomicMin((unsigned int*)addr, __float_as_uint(val));
}

// async 16B/lane global->LDS; lds base must be wave-uniform, lane l lands at base + l*16
__device__ __forceinline__ void async_copy16(void* lds, const void* g) {
    __builtin_amdgcn_global_load_lds(
        (__attribute__((address_space(1))) void*)g,
        (__attribute__((address_space(3))) void*)lds, 16, 0, 0);
}

__global__ __launch_bounds__(256) void init_kernel(float* scores, float* relacc,
                                                   float* hacc, unsigned* maskb,
                                                   int* selcnt) {
    int t = blockIdx.x * blockDim.x + threadIdx.x;
    if (t < B * NP)  { scores[t] = __int_as_float(0xFF800000); relacc[t] = 0.f; }
    if (t < B * HID) hacc[t] = 0.f;
    if (t < NIN)     maskb[t] = 0u;
    if (t < B)       selcnt[t] = 0;
}

__global__ __launch_bounds__(256) void scatter_maskbits(const int* __restrict__ idx,
                                                        unsigned* __restrict__ maskb) {
    int t = blockIdx.x * blockDim.x + threadIdx.x;
    if (t >= B * KIN) return;
    int b = t / KIN;
    atomicOr(&maskb[idx[t]], 1u << b);
}

// A fp32 [B][S][512] -> Apack bf16 [B][S][1024] = {hi(512) | lo(512)}
__global__ __launch_bounds__(256) void pack_A(const float* __restrict__ A,
                                              __bf16* __restrict__ Apack) {
    size_t t = (size_t)blockIdx.x * 256 + threadIdx.x;  // float4 index
    size_t f = t * 4;
    size_t rowi = f >> 9;
    int j = (int)(f & 511);
    float4 v = *(const float4*)(A + f);
    __bf16 h0 = (__bf16)v.x, h1 = (__bf16)v.y, h2 = (__bf16)v.z, h3 = (__bf16)v.w;
    bf16x4 hv = {h0, h1, h2, h3};
    bf16x4 lv = {(__bf16)(v.x - (float)h0), (__bf16)(v.y - (float)h1),
                 (__bf16)(v.z - (float)h2), (__bf16)(v.w - (float)h3)};
    __bf16* orow = Apack + rowi * 1024;
    *(bf16x4*)(orow + j) = hv;
    *(bf16x4*)(orow + 512 + j) = lv;
}

// Wpack[b][p][0:512]=hi(cw[p][idx[b][j]]), [512:1024]=lo
__global__ __launch_bounds__(256) void gather_pack_w(const float* __restrict__ cw,
                                                     const int* __restrict__ idx,
                                                     __bf16* __restrict__ wpack) {
    __shared__ int sidx[KIN];
    int b = blockIdx.y;
    int p0 = blockIdx.x * 8;
    for (int j = threadIdx.x; j < KIN; j += 256) sidx[j] = idx[b * KIN + j];
    __syncthreads();
    for (int r = 0; r < 8; ++r) {
        const float* row = cw + (size_t)(p0 + r) * NIN;
        __bf16* orow = wpack + ((size_t)b * NP + p0 + r) * 1024;
        for (int j = threadIdx.x; j < KIN; j += 256) {
            float x = row[sidx[j]];
            __bf16 hh = (__bf16)x;
            orow[j] = hh;
            orow[512 + j] = (__bf16)(x - (float)hh);
        }
    }
}

// ---------------- MFMA GEMM (128x128 tile, 4 waves of 64x64, 16x16x32 bf16) -----------
// C = A(MxK) * Bm(NxK)^T over NSEG segments of KSEG (split-fp32 trick when NSEG=3).
// EPI: 0 = gelu+colmax+atomicMax into scores[b][NP]
//      1 = gelu -> bf16 out[(b*S+row)*LDOUT + col]
//      2 = raw fp32 out[(b*S+row)*LDOUT + col]
template <int EPI, int NSEG, int KSEG, int LDA, int LDB, int BROWS, int LDOUT>
__global__ __launch_bounds__(256) void mfma_gemm(const __bf16* __restrict__ Ap,
                                                 const __bf16* __restrict__ Bp,
                                                 void* __restrict__ outp) {
    __shared__ __align__(16) __bf16 As[128 * 64];
    __shared__ __align__(16) __bf16 Ws[128 * 64];
    const int b = blockIdx.z;
    const int s0 = blockIdx.x * 128;
    const int p0 = blockIdx.y * 128;
    const int tid = threadIdx.x;
    const int w = tid >> 6, lane = tid & 63;
    const int wr = w >> 1, wc = w & 1;         // wave 2x2 layout within 128x128
    const int ldRow = lane >> 3;               // staging: 8 rows / issue
    const int ldCol = (lane & 7) * 8;          // 8 bf16 = 16B per lane
    const int fr = lane & 15;                  // frag row/col within 16
    const int fq = lane >> 4;                  // quad
    const __bf16* Ab = Ap + ((size_t)b * S + s0) * LDA;
    const __bf16* Bb = Bp + ((size_t)b * BROWS + p0) * LDB;

    f32x4 acc[4][4] = {};

    for (int seg = 0; seg < NSEG; ++seg) {
        const int aoff = (seg == 1) ? KSEG : 0;
        const int boff = (seg == 2) ? KSEG : 0;
        for (int k0 = 0; k0 < KSEG; k0 += 64) {
            __syncthreads();
#pragma unroll
            for (int i = 0; i < 4; ++i) {
                const __bf16* g = Ab + (size_t)(w * 32 + i * 8 + ldRow) * LDA + aoff + k0 + ldCol;
                async_copy16(&As[(w * 32 + i * 8) * 64], g);
            }
#pragma unroll
            for (int i = 0; i < 4; ++i) {
                const __bf16* g = Bb + (size_t)(w * 32 + i * 8 + ldRow) * LDB + boff + k0 + ldCol;
                async_copy16(&Ws[(w * 32 + i * 8) * 64], g);
            }
            __syncthreads();
#pragma unroll
            for (int ks = 0; ks < 2; ++ks) {
                bf16x8 af[4], bfr[4];
#pragma unroll
                for (int i = 0; i < 4; ++i)
                    af[i] = *(const bf16x8*)&As[(wr * 64 + i * 16 + fr) * 64 + ks * 32 + fq * 8];
#pragma unroll
                for (int j = 0; j < 4; ++j)
                    bfr[j] = *(const bf16x8*)&Ws[(wc * 64 + j * 16 + fr) * 64 + ks * 32 + fq * 8];
#pragma unroll
                for (int i = 0; i < 4; ++i)
#pragma unroll
                    for (int j = 0; j < 4; ++j)
                        acc[i][j] = __builtin_amdgcn_mfma_f32_16x16x32_bf16(af[i], bfr[j], acc[i][j], 0, 0, 0);
            }
        }
    }

    // C/D layout: col = lane&15 (fr), row = fq*4 + reg  [m89/m91 verified]
    if constexpr (EPI == 0) {
        float* scores = (float*)outp;
#pragma unroll
        for (int j = 0; j < 4; ++j) {
            float m = -INFINITY;
#pragma unroll
            for (int i = 0; i < 4; ++i)
#pragma unroll
                for (int r = 0; r < 4; ++r) m = fmaxf(m, gelu_exact(acc[i][j][r]));
            m = fmaxf(m, __shfl_xor(m, 16));
            m = fmaxf(m, __shfl_xor(m, 32));
            if (fq == 0)
                atomicMaxFloat(&scores[(size_t)b * LDOUT + p0 + wc * 64 + j * 16 + fr], m);
        }
    } else if constexpr (EPI == 1) {
        __bf16* o = (__bf16*)outp;
#pragma unroll
        for (int i = 0; i < 4; ++i)
#pragma unroll
            for (int r = 0; r < 4; ++r) {
                size_t row = (size_t)b * S + s0 + wr * 64 + i * 16 + fq * 4 + r;
#pragma unroll
                for (int j = 0; j < 4; ++j)
                    o[row * LDOUT + p0 + wc * 64 + j * 16 + fr] = (__bf16)gelu_exact(acc[i][j][r]);
            }
    } else {
        float* o = (float*)outp;
#pragma unroll
        for (int i = 0; i < 4; ++i)
#pragma unroll
            for (int r = 0; r < 4; ++r) {
                size_t row = (size_t)b * S + s0 + wr * 64 + i * 16 + fq * 4 + r;
#pragma unroll
                for (int j = 0; j < 4; ++j)
                    o[row * LDOUT + p0 + wc * 64 + j * 16 + fr] = acc[i][j][r];
            }
    }
}

// ---- MLP: read w1/w2 exactly once, loop batches in-register, partial-sum atomics ----
__global__ __launch_bounds__(256) void mlp1_part(const float* __restrict__ w1,
                                                 const unsigned* __restrict__ maskb,
                                                 float* __restrict__ hacc) {
    __shared__ unsigned smb[512];
    int i0 = blockIdx.x * 64;
    int c0 = blockIdx.y * 512;
    int tid = threadIdx.x;
    for (int c = tid; c < 512; c += 256) smb[c] = maskb[c0 + c];
    __syncthreads();
    int r = tid >> 2, cq = tid & 3;
    const float* row = w1 + (size_t)(i0 + r) * NIN + c0;
    float acc[B] = {};
    for (int it = 0; it < 32; ++it) {
        int c = it * 16 + cq * 4;
        float4 v = *(const float4*)(row + c);
        float vv[4] = {v.x, v.y, v.z, v.w};
#pragma unroll
        for (int e = 0; e < 4; ++e) {
            unsigned mb = smb[c + e];
#pragma unroll
            for (int bb = 0; bb < B; ++bb)
                if (mb & (1u << bb)) acc[bb] += vv[e];
        }
    }
#pragma unroll
    for (int bb = 0; bb < B; ++bb)
        atomicAdd(&hacc[bb * HID + i0 + r], acc[bb]);
}

__global__ __launch_bounds__(256) void fin1(const float* __restrict__ hacc,
                                            const float* __restrict__ b1,
                                            float* __restrict__ h) {
    int t = blockIdx.x * 256 + threadIdx.x;
    if (t < B * HID) h[t] = gelu_exact(hacc[t] + b1[t & (HID - 1)]);
}

__global__ __launch_bounds__(256) void mlp2_part(const float* __restrict__ w2,
                                                 const float* __restrict__ h,
                                                 float* __restrict__ relacc) {
    __shared__ float sh[B][512];
    int p0 = blockIdx.x * 64;
    int c0 = blockIdx.y * 512;
    int tid = threadIdx.x;
    for (int i = tid; i < B * 128; i += 256) {
        int bb = i >> 7, c4 = i & 127;
        *(float4*)&sh[bb][c4 * 4] = *(const float4*)&h[(size_t)bb * HID + c0 + c4 * 4];
    }
    __syncthreads();
    int r = tid >> 2, cq = tid & 3;
    const float* row = w2 + (size_t)(p0 + r) * HID + c0;
    float acc[B] = {};
    for (int it = 0; it < 32; ++it) {
        int c = it * 16 + cq * 4;
        float4 v = *(const float4*)(row + c);
#pragma unroll
        for (int bb = 0; bb < B; ++bb)
            acc[bb] += v.x * sh[bb][c] + v.y * sh[bb][c + 1] + v.z * sh[bb][c + 2] + v.w * sh[bb][c + 3];
    }
#pragma unroll
    for (int bb = 0; bb < B; ++bb)
        atomicAdd(&relacc[bb * NP + p0 + r], acc[bb]);
}

__global__ __launch_bounds__(256) void fin2(const float* __restrict__ relacc,
                                            const float* __restrict__ b2,
                                            float* __restrict__ scores) {
    int t = blockIdx.x * 256 + threadIdx.x;
    if (t >= B * NP) return;
    float rel = relacc[t] + b2[t & (NP - 1)];
    scores[t] *= 1.0f / (1.0f + expf(-rel));
}

// Exact top-k set via rank counting, jax.lax.top_k tie-break (lower index wins).
__global__ __launch_bounds__(256) void topk_select(const float* __restrict__ scores,
                                                   int* __restrict__ selidx,
                                                   int* __restrict__ selcnt) {
    __shared__ float sc[NP];
    int b = blockIdx.y;
    int p = blockIdx.x * 256 + threadIdx.x;
    for (int c = threadIdx.x; c < NP; c += 256) sc[c] = scores[(size_t)b * NP + c];
    __syncthreads();
    float my = sc[p];
    int cnt = 0;
    for (int q = 0; q < NP; ++q) {
        float v = sc[q];
        cnt += (v > my) || (v == my && q < p);
    }
    if (cnt < TOPK) {
        int pos = atomicAdd(&selcnt[b], 1);
        selidx[b * TOPK + pos] = p;  // order arbitrary; final einsum is a sum
    }
}

// Wsel[b][kk][0:512] = Wpack[b][sel[kk]][0:512]  (hi half only)
__global__ __launch_bounds__(256) void wsel_gather(const __bf16* __restrict__ wpack,
                                                   const int* __restrict__ selidx,
                                                   __bf16* __restrict__ wsel) {
    int kk = blockIdx.x, b = blockIdx.y;
    int sel = selidx[b * TOPK + kk];
    const unsigned* src = (const unsigned*)(wpack + ((size_t)b * NP + sel) * 1024);
    unsigned* dst = (unsigned*)(wsel + ((size_t)b * TOPK + kk) * 512);
    dst[threadIdx.x] = src[threadIdx.x];  // 256 uints = 512 bf16
}

// PT[b][d][kk] = bf16(proj[sel[kk]][d])  via LDS transpose
__global__ __launch_bounds__(256) void projT_gather(const float* __restrict__ proj,
                                                    const int* __restrict__ selidx,
                                                    __bf16* __restrict__ PT) {
    __shared__ float tile[64][68];
    __shared__ int sel[64];
    int b = blockIdx.z, d0 = blockIdx.x * 64, k0 = blockIdx.y * 64;
    int tid = threadIdx.x;
    if (tid < 64) sel[tid] = selidx[b * TOPK + k0 + tid];
    __syncthreads();
    for (int r = 0; r < 4; ++r) {
        int kk = r * 16 + (tid >> 4);
        float4 v = *(const float4*)&proj[(size_t)sel[kk] * DM + d0 + (tid & 15) * 4];
        *(float4*)&tile[kk][(tid & 15) * 4] = v;
    }
    __syncthreads();
    for (int r = 0; r < 16; ++r) {
        int dd = r * 4 + (tid >> 6);
        int kk = tid & 63;
        PT[((size_t)b * DM + d0 + dd) * TOPK + k0 + kk] = (__bf16)tile[kk][dd];
    }
}

extern "C" void kernel_launch(void* const* d_in, const int* in_sizes, int n_in,
                              void* d_out, int out_size, void* d_ws, size_t ws_size,
                              hipStream_t stream) {
    const float* A    = (const float*)d_in[0];
    const int*   idx  = (const int*)d_in[1];
    const float* cw   = (const float*)d_in[3];
    const float* proj = (const float*)d_in[4];
    const float* w1   = (const float*)d_in[5];
    const float* b1   = (const float*)d_in[6];
    const float* w2   = (const float*)d_in[7];
    const float* b2   = (const float*)d_in[8];
    float* out = (float*)d_out;

    char* ws = (char*)d_ws;
    size_t off = 0;
    auto alloc = [&](size_t bytes) {
        void* p = ws + off;
        off += (bytes + 255) & ~(size_t)255;
        return p;
    };
    __bf16* Apack = (__bf16*)alloc((size_t)B * S * 1024 * 2);    // 33.5 MB
    __bf16* Wpack = (__bf16*)alloc((size_t)B * NP * 1024 * 2);   // 67 MB
    __bf16* selpa = (__bf16*)alloc((size_t)B * S * TOPK * 2);    // 8.4 MB
    __bf16* PT    = (__bf16*)alloc((size_t)B * DM * TOPK * 2);   // 4.2 MB
    __bf16* Wsel  = (__bf16*)alloc((size_t)B * TOPK * 512 * 2);  // 2.1 MB
    float* scores = (float*)alloc((size_t)B * NP * 4);
    float* relacc = (float*)alloc((size_t)B * NP * 4);
    float* hacc   = (float*)alloc((size_t)B * HID * 4);
    float* h      = (float*)alloc((size_t)B * HID * 4);
    unsigned* maskb = (unsigned*)alloc((size_t)NIN * 4);
    int* selidx   = (int*)alloc((size_t)B * TOPK * 4);
    int* selcnt   = (int*)alloc((size_t)B * 4);

    init_kernel<<<dim3((B * HID + 255) / 256), 256, 0, stream>>>(scores, relacc, hacc, maskb, selcnt);
    scatter_maskbits<<<dim3((B * KIN + 255) / 256), 256, 0, stream>>>(idx, maskb);
    pack_A<<<dim3((B * S * KIN / 4) / 256), 256, 0, stream>>>(A, Apack);
    gather_pack_w<<<dim3(NP / 8, B), 256, 0, stream>>>(cw, idx, Wpack);

    // scores: split-fp32 (3 segments) bf16 MFMA, fused gelu+max epilogue
    mfma_gemm<0, 3, 512, 1024, 1024, NP, NP>
        <<<dim3(S / 128, NP / 128, B), 256, 0, stream>>>(Apack, Wpack, (void*)scores);

    mlp1_part<<<dim3(HID / 64, NIN / 512), 256, 0, stream>>>(w1, maskb, hacc);
    fin1<<<dim3((B * HID + 255) / 256), 256, 0, stream>>>(hacc, b1, h);
    mlp2_part<<<dim3(NP / 64, HID / 512), 256, 0, stream>>>(w2, h, relacc);
    fin2<<<dim3((B * NP + 255) / 256), 256, 0, stream>>>(relacc, b2, scores);

    topk_select<<<dim3(NP / 256, B), 256, 0, stream>>>(scores, selidx, selcnt);

    wsel_gather<<<dim3(TOPK, B), 256, 0, stream>>>(Wpack, selidx, Wsel);
    projT_gather<<<dim3(DM / 64, TOPK / 64, B), 256, 0, stream>>>(proj, selidx, PT);

    // selpa = gelu(A * Wsel^T) in bf16 (hi-only, 1 segment)
    mfma_gemm<1, 1, 512, 1024, 512, TOPK, TOPK>
        <<<dim3(S / 128, TOPK / 128, B), 256, 0, stream>>>(Apack, Wsel, (void*)selpa);

    // out = selpa * PT^T  (K=256, fp32 store)
    mfma_gemm<2, 1, 256, 256, 256, DM, DM>
        <<<dim3(S / 128, DM / 128, B), 256, 0, stream>>>(selpa, PT, (void*)out);
}

// Round 3
// 802.930 us; speedup vs baseline: 2.0142x; 1.0333x over previous
//
#include <hip/hip_runtime.h>
#include <math.h>

#define B 8
#define S 2048
#define KIN 512
#define NIN 2048
#define NP 4096
#define HID 4096
#define DM 1024
#define TOPK 256

typedef __bf16 bf16x8 __attribute__((ext_vector_type(8)));
typedef __bf16 bf16x4 __attribute__((ext_vector_type(4)));
typedef float f32x4 __attribute__((ext_vector_type(4)));

__device__ __forceinline__ float gelu_exact(float x) {
    return 0.5f * x * (1.0f + erff(x * 0.70710678118654752440f));
}

__device__ __forceinline__ void atomicMaxFloat(float* addr, float val) {
    if (val >= 0.0f) atomicMax((int*)addr, __float_as_int(val));
    else             atomicMin((unsigned int*)addr, __float_as_uint(val));
}

// async 16B/lane global->LDS; lds base must be wave-uniform, lane l lands at base + l*16
__device__ __forceinline__ void async_copy16(void* lds, const void* g) {
    __builtin_amdgcn_global_load_lds(
        (__attribute__((address_space(1))) void*)g,
        (__attribute__((address_space(3))) void*)lds, 16, 0, 0);
}

__global__ __launch_bounds__(256) void init_kernel(float* scores, float* relacc,
                                                   float* hacc, unsigned* maskb,
                                                   int* selcnt) {
    int t = blockIdx.x * blockDim.x + threadIdx.x;
    if (t < B * NP)  { scores[t] = __int_as_float(0xFF800000); relacc[t] = 0.f; }
    if (t < B * HID) hacc[t] = 0.f;
    if (t < NIN)     maskb[t] = 0u;
    if (t < B)       selcnt[t] = 0;
}

__global__ __launch_bounds__(256) void scatter_maskbits(const int* __restrict__ idx,
                                                        unsigned* __restrict__ maskb) {
    int t = blockIdx.x * blockDim.x + threadIdx.x;
    if (t >= B * KIN) return;
    int b = t / KIN;
    atomicOr(&maskb[idx[t]], 1u << b);
}

// A fp32 [B][S][512] -> Apack bf16 [B][S][1024] = {hi(512) | lo(512)}
__global__ __launch_bounds__(256) void pack_A(const float* __restrict__ A,
                                              __bf16* __restrict__ Apack) {
    size_t t = (size_t)blockIdx.x * 256 + threadIdx.x;  // float4 index
    size_t f = t * 4;
    size_t rowi = f >> 9;
    int j = (int)(f & 511);
    float4 v = *(const float4*)(A + f);
    __bf16 h0 = (__bf16)v.x, h1 = (__bf16)v.y, h2 = (__bf16)v.z, h3 = (__bf16)v.w;
    bf16x4 hv = {h0, h1, h2, h3};
    bf16x4 lv = {(__bf16)(v.x - (float)h0), (__bf16)(v.y - (float)h1),
                 (__bf16)(v.z - (float)h2), (__bf16)(v.w - (float)h3)};
    __bf16* orow = Apack + rowi * 1024;
    *(bf16x4*)(orow + j) = hv;
    *(bf16x4*)(orow + 512 + j) = lv;
}

// One pass over cw: each block owns 4 cw rows in LDS, gathers for all 8 batches.
// HBM: read cw once (33.5 MB) + idx, write Wpack (67 MB), all coalesced.
__global__ __launch_bounds__(256) void gather_pack_w(const float* __restrict__ cw,
                                                     const int* __restrict__ idx,
                                                     __bf16* __restrict__ wpack) {
    __shared__ float rowbuf[4][NIN];   // 32 KB
    __shared__ int sidx[B][KIN];       // 16 KB
    int p0 = blockIdx.x * 4;
    int tid = threadIdx.x;
    for (int t = tid; t < B * KIN; t += 256) sidx[t >> 9][t & 511] = idx[t];
#pragma unroll
    for (int r = 0; r < 4; ++r)
        for (int c = tid; c < NIN / 4; c += 256)
            *(float4*)&rowbuf[r][c * 4] = *(const float4*)&cw[(size_t)(p0 + r) * NIN + c * 4];
    __syncthreads();
#pragma unroll
    for (int r = 0; r < 4; ++r) {
        int p = p0 + r;
        for (int b = 0; b < B; ++b) {
            __bf16* orow = wpack + ((size_t)b * NP + p) * 1024;
            for (int j = tid; j < KIN; j += 256) {
                float x = rowbuf[r][sidx[b][j]];
                __bf16 hh = (__bf16)x;
                orow[j] = hh;
                orow[512 + j] = (__bf16)(x - (float)hh);
            }
        }
    }
}

// ---------------- MFMA GEMM (128x128 tile, 4 waves of 64x64, 16x16x32 bf16) -----------
// C = A(MxK) * Bm(NxK)^T over NSEG segments of KSEG (split-fp32 trick when NSEG=3).
// LDS layout is XOR-swizzled: 16B chunk c of row r stored at chunk c^(r&7).
// Staging fetches the permuted global chunk so global_load_lds (fixed lane->slot)
// lands it right; fragment reads XOR the chunk index. Kills the 16-way bank
// conflicts of the naive row-major layout (lane stride 128B = same bank).
// EPI: 0 = gelu+colmax+atomicMax into scores[b][NP]
//      1 = gelu -> bf16 out[(b*S+row)*LDOUT + col]
//      2 = raw fp32 out[(b*S+row)*LDOUT + col]
template <int EPI, int NSEG, int KSEG, int LDA, int LDB, int BROWS, int LDOUT>
__global__ __launch_bounds__(256) void mfma_gemm(const __bf16* __restrict__ Ap,
                                                 const __bf16* __restrict__ Bp,
                                                 void* __restrict__ outp) {
    __shared__ __align__(16) __bf16 As[128 * 64];
    __shared__ __align__(16) __bf16 Ws[128 * 64];
    const int b = blockIdx.z;
    const int s0 = blockIdx.x * 128;
    const int p0 = blockIdx.y * 128;
    const int tid = threadIdx.x;
    const int w = tid >> 6, lane = tid & 63;
    const int wr = w >> 1, wc = w & 1;         // wave 2x2 layout within 128x128
    const int ldRow = lane >> 3;               // staging: 8 rows / issue
    const int ldCol = ((lane & 7) ^ (ldRow & 7)) * 8;  // swizzled global chunk
    const int fr = lane & 15;                  // frag row/col within 16
    const int fq = lane >> 4;                  // quad
    const __bf16* Ab = Ap + ((size_t)b * S + s0) * LDA;
    const __bf16* Bb = Bp + ((size_t)b * BROWS + p0) * LDB;

    f32x4 acc[4][4] = {};

    for (int seg = 0; seg < NSEG; ++seg) {
        const int aoff = (seg == 1) ? KSEG : 0;
        const int boff = (seg == 2) ? KSEG : 0;
        for (int k0 = 0; k0 < KSEG; k0 += 64) {
            __syncthreads();
#pragma unroll
            for (int i = 0; i < 4; ++i) {
                const __bf16* g = Ab + (size_t)(w * 32 + i * 8 + ldRow) * LDA + aoff + k0 + ldCol;
                async_copy16(&As[(w * 32 + i * 8) * 64], g);
            }
#pragma unroll
            for (int i = 0; i < 4; ++i) {
                const __bf16* g = Bb + (size_t)(w * 32 + i * 8 + ldRow) * LDB + boff + k0 + ldCol;
                async_copy16(&Ws[(w * 32 + i * 8) * 64], g);
            }
            __syncthreads();
#pragma unroll
            for (int ks = 0; ks < 2; ++ks) {
                bf16x8 af[4], bfr[4];
#pragma unroll
                for (int i = 0; i < 4; ++i) {
                    int R = wr * 64 + i * 16 + fr;
                    af[i] = *(const bf16x8*)&As[R * 64 + (((ks * 4 + fq) ^ (R & 7)) * 8)];
                }
#pragma unroll
                for (int j = 0; j < 4; ++j) {
                    int R = wc * 64 + j * 16 + fr;
                    bfr[j] = *(const bf16x8*)&Ws[R * 64 + (((ks * 4 + fq) ^ (R & 7)) * 8)];
                }
#pragma unroll
                for (int i = 0; i < 4; ++i)
#pragma unroll
                    for (int j = 0; j < 4; ++j)
                        acc[i][j] = __builtin_amdgcn_mfma_f32_16x16x32_bf16(af[i], bfr[j], acc[i][j], 0, 0, 0);
            }
        }
    }

    // C/D layout: col = lane&15 (fr), row = fq*4 + reg  [m89/m91 verified]
    if constexpr (EPI == 0) {
        float* scores = (float*)outp;
#pragma unroll
        for (int j = 0; j < 4; ++j) {
            float m = -INFINITY;
#pragma unroll
            for (int i = 0; i < 4; ++i)
#pragma unroll
                for (int r = 0; r < 4; ++r) m = fmaxf(m, gelu_exact(acc[i][j][r]));
            m = fmaxf(m, __shfl_xor(m, 16));
            m = fmaxf(m, __shfl_xor(m, 32));
            if (fq == 0)
                atomicMaxFloat(&scores[(size_t)b * LDOUT + p0 + wc * 64 + j * 16 + fr], m);
        }
    } else if constexpr (EPI == 1) {
        __bf16* o = (__bf16*)outp;
#pragma unroll
        for (int i = 0; i < 4; ++i)
#pragma unroll
            for (int r = 0; r < 4; ++r) {
                size_t row = (size_t)b * S + s0 + wr * 64 + i * 16 + fq * 4 + r;
#pragma unroll
                for (int j = 0; j < 4; ++j)
                    o[row * LDOUT + p0 + wc * 64 + j * 16 + fr] = (__bf16)gelu_exact(acc[i][j][r]);
            }
    } else {
        float* o = (float*)outp;
#pragma unroll
        for (int i = 0; i < 4; ++i)
#pragma unroll
            for (int r = 0; r < 4; ++r) {
                size_t row = (size_t)b * S + s0 + wr * 64 + i * 16 + fq * 4 + r;
#pragma unroll
                for (int j = 0; j < 4; ++j)
                    o[row * LDOUT + p0 + wc * 64 + j * 16 + fr] = acc[i][j][r];
            }
    }
}

// ---- MLP: read w1/w2 exactly once, loop batches in-register, partial-sum atomics ----
__global__ __launch_bounds__(256) void mlp1_part(const float* __restrict__ w1,
                                                 const unsigned* __restrict__ maskb,
                                                 float* __restrict__ hacc) {
    __shared__ unsigned smb[512];
    int i0 = blockIdx.x * 64;
    int c0 = blockIdx.y * 512;
    int tid = threadIdx.x;
    for (int c = tid; c < 512; c += 256) smb[c] = maskb[c0 + c];
    __syncthreads();
    int r = tid >> 2, cq = tid & 3;
    const float* row = w1 + (size_t)(i0 + r) * NIN + c0;
    float acc[B] = {};
    for (int it = 0; it < 32; ++it) {
        int c = it * 16 + cq * 4;
        float4 v = *(const float4*)(row + c);
        float vv[4] = {v.x, v.y, v.z, v.w};
#pragma unroll
        for (int e = 0; e < 4; ++e) {
            unsigned mb = smb[c + e];
#pragma unroll
            for (int bb = 0; bb < B; ++bb)
                if (mb & (1u << bb)) acc[bb] += vv[e];
        }
    }
#pragma unroll
    for (int bb = 0; bb < B; ++bb)
        atomicAdd(&hacc[bb * HID + i0 + r], acc[bb]);
}

__global__ __launch_bounds__(256) void fin1(const float* __restrict__ hacc,
                                            const float* __restrict__ b1,
                                            float* __restrict__ h) {
    int t = blockIdx.x * 256 + threadIdx.x;
    if (t < B * HID) h[t] = gelu_exact(hacc[t] + b1[t & (HID - 1)]);
}

__global__ __launch_bounds__(256) void mlp2_part(const float* __restrict__ w2,
                                                 const float* __restrict__ h,
                                                 float* __restrict__ relacc) {
    __shared__ float sh[B][512];
    int p0 = blockIdx.x * 64;
    int c0 = blockIdx.y * 512;
    int tid = threadIdx.x;
    for (int i = tid; i < B * 128; i += 256) {
        int bb = i >> 7, c4 = i & 127;
        *(float4*)&sh[bb][c4 * 4] = *(const float4*)&h[(size_t)bb * HID + c0 + c4 * 4];
    }
    __syncthreads();
    int r = tid >> 2, cq = tid & 3;
    const float* row = w2 + (size_t)(p0 + r) * HID + c0;
    float acc[B] = {};
    for (int it = 0; it < 32; ++it) {
        int c = it * 16 + cq * 4;
        float4 v = *(const float4*)(row + c);
#pragma unroll
        for (int bb = 0; bb < B; ++bb)
            acc[bb] += v.x * sh[bb][c] + v.y * sh[bb][c + 1] + v.z * sh[bb][c + 2] + v.w * sh[bb][c + 3];
    }
#pragma unroll
    for (int bb = 0; bb < B; ++bb)
        atomicAdd(&relacc[bb * NP + p0 + r], acc[bb]);
}

__global__ __launch_bounds__(256) void fin2(const float* __restrict__ relacc,
                                            const float* __restrict__ b2,
                                            float* __restrict__ scores) {
    int t = blockIdx.x * 256 + threadIdx.x;
    if (t >= B * NP) return;
    float rel = relacc[t] + b2[t & (NP - 1)];
    scores[t] *= 1.0f / (1.0f + expf(-rel));
}

// Exact top-k set via rank counting, jax.lax.top_k tie-break (lower index wins).
__global__ __launch_bounds__(256) void topk_select(const float* __restrict__ scores,
                                                   int* __restrict__ selidx,
                                                   int* __restrict__ selcnt) {
    __shared__ float sc[NP];
    int b = blockIdx.y;
    int p = blockIdx.x * 256 + threadIdx.x;
    for (int c = threadIdx.x; c < NP; c += 256) sc[c] = scores[(size_t)b * NP + c];
    __syncthreads();
    float my = sc[p];
    int cnt = 0;
    for (int q = 0; q < NP; ++q) {
        float v = sc[q];
        cnt += (v > my) || (v == my && q < p);
    }
    if (cnt < TOPK) {
        int pos = atomicAdd(&selcnt[b], 1);
        selidx[b * TOPK + pos] = p;  // order arbitrary; final einsum is a sum
    }
}

// Wsel[b][kk][0:512] = Wpack[b][sel[kk]][0:512]  (hi half only)
__global__ __launch_bounds__(256) void wsel_gather(const __bf16* __restrict__ wpack,
                                                   const int* __restrict__ selidx,
                                                   __bf16* __restrict__ wsel) {
    int kk = blockIdx.x, b = blockIdx.y;
    int sel = selidx[b * TOPK + kk];
    const unsigned* src = (const unsigned*)(wpack + ((size_t)b * NP + sel) * 1024);
    unsigned* dst = (unsigned*)(wsel + ((size_t)b * TOPK + kk) * 512);
    dst[threadIdx.x] = src[threadIdx.x];  // 256 uints = 512 bf16
}

// PT[b][d][kk] = bf16(proj[sel[kk]][d])  via LDS transpose
__global__ __launch_bounds__(256) void projT_gather(const float* __restrict__ proj,
                                                    const int* __restrict__ selidx,
                                                    __bf16* __restrict__ PT) {
    __shared__ float tile[64][68];
    __shared__ int sel[64];
    int b = blockIdx.z, d0 = blockIdx.x * 64, k0 = blockIdx.y * 64;
    int tid = threadIdx.x;
    if (tid < 64) sel[tid] = selidx[b * TOPK + k0 + tid];
    __syncthreads();
    for (int r = 0; r < 4; ++r) {
        int kk = r * 16 + (tid >> 4);
        float4 v = *(const float4*)&proj[(size_t)sel[kk] * DM + d0 + (tid & 15) * 4];
        *(float4*)&tile[kk][(tid & 15) * 4] = v;
    }
    __syncthreads();
    for (int r = 0; r < 16; ++r) {
        int dd = r * 4 + (tid >> 6);
        int kk = tid & 63;
        PT[((size_t)b * DM + d0 + dd) * TOPK + k0 + kk] = (__bf16)tile[kk][dd];
    }
}

extern "C" void kernel_launch(void* const* d_in, const int* in_sizes, int n_in,
                              void* d_out, int out_size, void* d_ws, size_t ws_size,
                              hipStream_t stream) {
    const float* A    = (const float*)d_in[0];
    const int*   idx  = (const int*)d_in[1];
    const float* cw   = (const float*)d_in[3];
    const float* proj = (const float*)d_in[4];
    const float* w1   = (const float*)d_in[5];
    const float* b1   = (const float*)d_in[6];
    const float* w2   = (const float*)d_in[7];
    const float* b2   = (const float*)d_in[8];
    float* out = (float*)d_out;

    char* ws = (char*)d_ws;
    size_t off = 0;
    auto alloc = [&](size_t bytes) {
        void* p = ws + off;
        off += (bytes + 255) & ~(size_t)255;
        return p;
    };
    __bf16* Apack = (__bf16*)alloc((size_t)B * S * 1024 * 2);    // 33.5 MB
    __bf16* Wpack = (__bf16*)alloc((size_t)B * NP * 1024 * 2);   // 67 MB
    __bf16* selpa = (__bf16*)alloc((size_t)B * S * TOPK * 2);    // 8.4 MB
    __bf16* PT    = (__bf16*)alloc((size_t)B * DM * TOPK * 2);   // 4.2 MB
    __bf16* Wsel  = (__bf16*)alloc((size_t)B * TOPK * 512 * 2);  // 2.1 MB
    float* scores = (float*)alloc((size_t)B * NP * 4);
    float* relacc = (float*)alloc((size_t)B * NP * 4);
    float* hacc   = (float*)alloc((size_t)B * HID * 4);
    float* h      = (float*)alloc((size_t)B * HID * 4);
    unsigned* maskb = (unsigned*)alloc((size_t)NIN * 4);
    int* selidx   = (int*)alloc((size_t)B * TOPK * 4);
    int* selcnt   = (int*)alloc((size_t)B * 4);

    init_kernel<<<dim3((B * HID + 255) / 256), 256, 0, stream>>>(scores, relacc, hacc, maskb, selcnt);
    scatter_maskbits<<<dim3((B * KIN + 255) / 256), 256, 0, stream>>>(idx, maskb);
    pack_A<<<dim3((B * S * KIN / 4) / 256), 256, 0, stream>>>(A, Apack);
    gather_pack_w<<<dim3(NP / 4), 256, 0, stream>>>(cw, idx, Wpack);

    // scores: split-fp32 (3 segments) bf16 MFMA, fused gelu+max epilogue
    mfma_gemm<0, 3, 512, 1024, 1024, NP, NP>
        <<<dim3(S / 128, NP / 128, B), 256, 0, stream>>>(Apack, Wpack, (void*)scores);

    mlp1_part<<<dim3(HID / 64, NIN / 512), 256, 0, stream>>>(w1, maskb, hacc);
    fin1<<<dim3((B * HID + 255) / 256), 256, 0, stream>>>(hacc, b1, h);
    mlp2_part<<<dim3(NP / 64, HID / 512), 256, 0, stream>>>(w2, h, relacc);
    fin2<<<dim3((B * NP + 255) / 256), 256, 0, stream>>>(relacc, b2, scores);

    topk_select<<<dim3(NP / 256, B), 256, 0, stream>>>(scores, selidx, selcnt);

    wsel_gather<<<dim3(TOPK, B), 256, 0, stream>>>(Wpack, selidx, Wsel);
    projT_gather<<<dim3(DM / 64, TOPK / 64, B), 256, 0, stream>>>(proj, selidx, PT);

    // selpa = gelu(A * Wsel^T) in bf16 (hi-only, 1 segment)
    mfma_gemm<1, 1, 512, 1024, 512, TOPK, TOPK>
        <<<dim3(S / 128, TOPK / 128, B), 256, 0, stream>>>(Apack, Wsel, (void*)selpa);

    // out = selpa * PT^T  (K=256, fp32 store)
    mfma_gemm<2, 1, 256, 256, 256, DM, DM>
        <<<dim3(S / 128, DM / 128, B), 256, 0, stream>>>(selpa, PT, (void*)out);
}